// Round 1
// 837.981 us; speedup vs baseline: 1.0151x; 1.0151x over previous
//
#include <hip/hip_runtime.h>

// STATE=4096, CDIM=1024, fan_in=5121. RK4 x 4 steps = 16 aug-dynamics evals.
// Weights: state rows + t-row (4097 x 4096) cached in ws as bf16; c-rows'
// contribution (+bias) precomputed once in fp32 (cpart1/2).
#define N      4096
#define NROWS  4097
#define NC     1024
#define STEPS  4
#define TPB    256

typedef unsigned short us8 __attribute__((ext_vector_type(8)));

__device__ __forceinline__ float bf2f(unsigned short u) {
  union { unsigned int i; float f; } v; v.i = ((unsigned int)u) << 16; return v.f;
}
__device__ __forceinline__ unsigned short f2bf(float f) {
  union { float f; unsigned int i; } v; v.f = f;
  const unsigned int u = v.i;
  return (unsigned short)((u + 0x7FFFu + ((u >> 16) & 1u)) >> 16);  // RNE
}
__device__ __forceinline__ float sigf(float x) { return 1.0f / (1.0f + __expf(-x)); }

// ---------------------------------------------------------------------------
__global__ __launch_bounds__(TPB) void k_init(const float* __restrict__ h,
                                              const float* __restrict__ b1,
                                              const float* __restrict__ b2,
                                              float* __restrict__ ycur,
                                              float* __restrict__ cp1,
                                              float* __restrict__ cp2,
                                              float* __restrict__ rk) {
  const int j = blockIdx.x * TPB + threadIdx.x;
  if (j < N) { ycur[j] = h[j]; cp1[j] = b1[j]; cp2[j] = b2[j]; }
  if (j < 16) rk[j] = 0.f;
}

// W rows [NC, NC+NROWS) fp32 -> bf16 (native [NROWS][N] layout, RNE).
// 4 rows per block, 16 float4 loads / 8 us8 stores per thread for ILP.
__global__ __launch_bounds__(TPB) void k_conv(const float* __restrict__ W1,
                                              const float* __restrict__ W2,
                                              unsigned short* __restrict__ W1bf,
                                              unsigned short* __restrict__ W2bf) {
  const int r0 = blockIdx.x * 4;
  const float* __restrict__ srcM = (blockIdx.y ? W2 : W1) + (size_t)NC * N;
  unsigned short* __restrict__ dstM = blockIdx.y ? W2bf : W1bf;
  const int col = threadIdx.x * 16;
#pragma unroll
  for (int rr = 0; rr < 4; ++rr) {
    const int row = r0 + rr;
    if (row < NROWS) {
      const float* __restrict__ s = srcM + (size_t)row * N + col;
      unsigned short* __restrict__ d = dstM + (size_t)row * N + col;
      const float4 a = *reinterpret_cast<const float4*>(s);
      const float4 b = *reinterpret_cast<const float4*>(s + 4);
      const float4 e = *reinterpret_cast<const float4*>(s + 8);
      const float4 g = *reinterpret_cast<const float4*>(s + 12);
      us8 o1, o2;
      o1[0] = f2bf(a.x); o1[1] = f2bf(a.y); o1[2] = f2bf(a.z); o1[3] = f2bf(a.w);
      o1[4] = f2bf(b.x); o1[5] = f2bf(b.y); o1[6] = f2bf(b.z); o1[7] = f2bf(b.w);
      o2[0] = f2bf(e.x); o2[1] = f2bf(e.y); o2[2] = f2bf(e.z); o2[3] = f2bf(e.w);
      o2[4] = f2bf(g.x); o2[5] = f2bf(g.y); o2[6] = f2bf(g.z); o2[7] = f2bf(g.w);
      *reinterpret_cast<us8*>(d) = o1;
      *reinterpret_cast<us8*>(d + 8) = o2;
    }
  }
}

// cp += c @ W[0:NC]  (fp32, once). grid (16, 8, 2), block 256.
__global__ __launch_bounds__(TPB) void k_cpart(const float* __restrict__ W1,
                                               const float* __restrict__ W2,
                                               const float* __restrict__ c,
                                               float* __restrict__ cp1,
                                               float* __restrict__ cp2) {
  const float* __restrict__ W = blockIdx.z ? W2 : W1;
  float* __restrict__ cp = blockIdx.z ? cp2 : cp1;
  __shared__ float xs[128];
  __shared__ float red[8][256];
  const int tid = threadIdx.x;
  const int cb = blockIdx.x, rc = blockIdx.y;
  const int r0 = rc * 128;
  if (tid < 128) xs[tid] = c[r0 + tid];
  __syncthreads();
  const int cg = tid & 31, rg = tid >> 5;
  const float* __restrict__ wbase = W + (size_t)r0 * N + cb * 256 + cg * 8;
  float a[8] = {0,0,0,0,0,0,0,0};
#pragma unroll
  for (int k = 0; k < 16; ++k) {
    const int r = rg + (k << 3);
    const float xv = xs[r];
    const float4 wa = *reinterpret_cast<const float4*>(wbase + (size_t)r * N);
    const float4 wb = *reinterpret_cast<const float4*>(wbase + (size_t)r * N + 4);
    a[0] = fmaf(wa.x, xv, a[0]); a[1] = fmaf(wa.y, xv, a[1]);
    a[2] = fmaf(wa.z, xv, a[2]); a[3] = fmaf(wa.w, xv, a[3]);
    a[4] = fmaf(wb.x, xv, a[4]); a[5] = fmaf(wb.y, xv, a[5]);
    a[6] = fmaf(wb.z, xv, a[6]); a[7] = fmaf(wb.w, xv, a[7]);
  }
#pragma unroll
  for (int e = 0; e < 8; ++e) red[rg][cg * 8 + e] = a[e];
  __syncthreads();
  float ssum = 0.f;
#pragma unroll
  for (int g = 0; g < 8; ++g) ssum += red[g][tid];
  atomicAdd(&cp[cb * 256 + tid], ssum);
}

// ---------------------------------------------------------------------------
// One fused phase: prefetch this block's weight tile into registers (latency
// overlaps the reduce/epilogue head), then reduce previous partials for my
// 128-row chunk -> epilogue (per mode) -> build x chunk -> matvec from the
// prefetched registers -> write partials.
// Modes: 0=FIRST(x=sig(h)), 1=P2(u1), 2=P3(f,tangent-L1 in), 3=P4(du1,RK),
//        4=PD(df,rk,next-stage x1). grid (16 colblocks, 32 rowchunks).
// ---------------------------------------------------------------------------
__global__ __launch_bounds__(TPB, 2) void k_phase(
    int mode,
    const unsigned short* __restrict__ Wbf,
    const float* __restrict__ part_in,
    float* __restrict__ part_out,
    const float* __restrict__ cpart,
    const float* __restrict__ tptr,
    float* __restrict__ u1,
    float* __restrict__ fcur,
    const float* __restrict__ fprev,
    float* __restrict__ ycur,
    float* __restrict__ ksum,
    float* __restrict__ rk,
    int rkIdx, int s, float csv, float tmul, float tadd) {
  __shared__ float xs[128];
  __shared__ float red[8][256];
  const int tid = threadIdx.x;
  const int cb = blockIdx.x, rc = blockIdx.y;
  const int j0 = rc * 128;
  const int cg = tid & 31, rg = tid >> 5;

  // ---- weight prefetch: addresses depend only on blockIdx/threadIdx ----
  const unsigned short* __restrict__ wbase =
      Wbf + (size_t)j0 * N + cb * 256 + cg * 8;
  us8 w[16];
#pragma unroll
  for (int k = 0; k < 16; ++k)
    w[k] = *reinterpret_cast<const us8*>(wbase + (size_t)(rg + (k << 3)) * N);
  const bool doT = (rc == 31 && rg == 0);
  us8 wt = w[0];
  if (doT)
    wt = *reinterpret_cast<const us8*>(Wbf + (size_t)N * N + cb * 256 + cg * 8);

  const float dtv = tptr[0] * (1.0f / STEPS);

  if (tid < 128) {
    const int j = j0 + tid;
    float xv;
    if (mode == 0) {                       // FIRST: x1 = sig(h)
      xv = sigf(ycur[j]);
    } else {
      float ssum = 0.f;
#pragma unroll 8
      for (int r = 0; r < 32; ++r) ssum += part_in[(r << 12) + j];
      if (mode == 1) {                     // P2: u1 = red + cpart1; x2 = sig(u1)
        const float u = ssum + cpart[j];
        if (cb == 0) u1[j] = u;
        xv = sigf(u);
      } else if (mode == 2) {              // P3: f = red + cpart2; v1 = s0'(ys)*f
        const float fv = ssum + cpart[j];
        if (cb == 0) fcur[j] = fv;
        float ys = ycur[j];
        if (csv != 0.f) ys = fmaf(csv * dtv, fprev[j], ys);
        const float s0 = sigf(ys);
        xv = s0 * (1.f - s0) * fv;
      } else if (mode == 3) {              // P4: du1 = red; v2 = s1'(u1)*du1; RK
        if (cb == 0) {
          const float fc = fcur[j];
          if (s == 0)      ksum[j] = fc;
          else if (s < 3)  ksum[j] = fmaf(2.f, fc, ksum[j]);
          else             ycur[j] = fmaf(dtv * (1.f / 6.f), ksum[j] + fc, ycur[j]);
        }
        const float s1 = sigf(u1[j]);
        xv = s1 * (1.f - s1) * ssum;
      } else {                             // PD: df = red; rk += df^2; x1 next
        float v = ssum * ssum;
#pragma unroll
        for (int off = 32; off >= 1; off >>= 1) v += __shfl_down(v, off);
        if (cb == 0 && (tid & 63) == 0) atomicAdd(&rk[rkIdx], v);
        float ys = ycur[j];
        if (csv != 0.f) ys = fmaf(csv * dtv, fprev[j], ys);
        xv = sigf(ys);
      }
    }
    xs[tid] = xv;
  }

  // Pin the prefetched tile in registers on THIS side of the barrier so the
  // scheduler cannot sink the loads past it (loads may legally cross fences).
#pragma unroll
  for (int k = 0; k < 16; ++k) asm volatile("" :: "v"(w[k]));
  __syncthreads();

  float a[8] = {0,0,0,0,0,0,0,0};
#pragma unroll
  for (int k = 0; k < 16; ++k) {
    const float xv = xs[rg + (k << 3)];
#pragma unroll
    for (int e = 0; e < 8; ++e) a[e] = fmaf(bf2f(w[k][e]), xv, a[e]);
  }
  if (doT) {                               // t-row contribution
    const float coef = fmaf(tmul, dtv, tadd);
#pragma unroll
    for (int e = 0; e < 8; ++e) a[e] = fmaf(bf2f(wt[e]), coef, a[e]);
  }
#pragma unroll
  for (int e = 0; e < 8; ++e) red[rg][cg * 8 + e] = a[e];
  __syncthreads();
  float ssum = 0.f;
#pragma unroll
  for (int g = 0; g < 8; ++g) ssum += red[g][tid];
  part_out[(rc << 12) + cb * 256 + tid] = ssum;
}

// Reduce the final P4 partials -> rk[15]; copy ycur -> out.
__global__ __launch_bounds__(128) void k_last(const float* __restrict__ part_in,
                                              const float* __restrict__ ycur,
                                              float* __restrict__ rk,
                                              float* __restrict__ out) {
  const int tid = threadIdx.x;
  const int j = blockIdx.x * 128 + tid;
  float df = 0.f;
#pragma unroll 8
  for (int r = 0; r < 32; ++r) df += part_in[(r << 12) + j];
  float v = df * df;
#pragma unroll
  for (int off = 32; off >= 1; off >>= 1) v += __shfl_down(v, off);
  if ((tid & 63) == 0) atomicAdd(&rk[15], v);
  out[j] = ycur[j];
}

__global__ void k_out(const float* __restrict__ rk, const float* __restrict__ tptr,
                      float* __restrict__ out) {
  if (threadIdx.x == 0) {
    const float dtv = tptr[0] * (1.0f / STEPS);
    float r = 0.f;
    for (int st = 0; st < STEPS; ++st)
      r += rk[4 * st] + 2.f * rk[4 * st + 1] + 2.f * rk[4 * st + 2] + rk[4 * st + 3];
    out[N] = r * (dtv / 6.f) * (1.0f / N);
  }
}

// ---------------------------------------------------------------------------
extern "C" void kernel_launch(void* const* d_in, const int* in_sizes, int n_in,
                              void* d_out, int out_size, void* d_ws, size_t ws_size,
                              hipStream_t stream) {
  const float* h  = (const float*)d_in[0];
  const float* t  = (const float*)d_in[1];
  const float* c  = (const float*)d_in[2];
  const float* W1 = (const float*)d_in[3];
  const float* b1 = (const float*)d_in[4];
  const float* W2 = (const float*)d_in[5];
  const float* b2 = (const float*)d_in[6];
  float* out = (float*)d_out;

  // ws: W1bf | W2bf (bf16, 33.56 MB each) | fp32 buffers (~1.2 MB).
  char* ws = (char*)d_ws;
  const size_t wb = (size_t)NROWS * N * sizeof(unsigned short);
  unsigned short* W1bf = (unsigned short*)ws;
  unsigned short* W2bf = (unsigned short*)(ws + wb);
  float* fp = (float*)(ws + 2 * wb);
  float* partA = fp;                     // 32*4096
  float* partB = partA + 32 * N;
  float* cp1   = partB + 32 * N;
  float* cp2   = cp1 + N;
  float* u1    = cp2 + N;
  float* fb0   = u1 + N;
  float* fb1   = fb0 + N;
  float* ycur  = fb1 + N;
  float* ksum  = ycur + N;
  float* rk    = ksum + N;               // 16

  k_init<<<16, TPB, 0, stream>>>(h, b1, b2, ycur, cp1, cp2, rk);
  k_conv<<<dim3((NROWS + 3) / 4, 2), TPB, 0, stream>>>(W1, W2, W1bf, W2bf);
  k_cpart<<<dim3(16, 8, 2), TPB, 0, stream>>>(W1, W2, c, cp1, cp2);

  const float csv[4] = {0.f, 0.5f, 0.5f, 1.f};
  float* bufs[2] = {partA, partB};
  int flip = 0;
  for (int i = 0; i < 16; ++i) {
    const int step = i >> 2, s = i & 3;
    const float tsv = (float)step + csv[s];
    float* fcur  = (i & 1) ? fb1 : fb0;
    float* fprev = (i & 1) ? fb0 : fb1;

    // P1: u1 partials = x1 @ W1_state   (FIRST for i=0, PD otherwise)
    {
      float* po = bufs[flip]; const float* pi = bufs[flip ^ 1]; flip ^= 1;
      if (i == 0)
        k_phase<<<dim3(16, 32), TPB, 0, stream>>>(0, W1bf, pi, po, cp1, t,
            u1, fcur, fprev, ycur, ksum, rk, 0, s, 0.f, 0.f, 0.f);
      else
        k_phase<<<dim3(16, 32), TPB, 0, stream>>>(4, W1bf, pi, po, cp1, t,
            u1, fcur, fprev, ycur, ksum, rk, i - 1, s, csv[s], tsv, 0.f);
    }
    // P2: f partials = sig(u1+cp1) @ W2_state
    {
      float* po = bufs[flip]; const float* pi = bufs[flip ^ 1]; flip ^= 1;
      k_phase<<<dim3(16, 32), TPB, 0, stream>>>(1, W2bf, pi, po, cp1, t,
          u1, fcur, fprev, ycur, ksum, rk, 0, s, csv[s], tsv, 0.f);
    }
    // P3: du1 partials = (sig'(ys)*f) @ W1_state, t-coef 1
    {
      float* po = bufs[flip]; const float* pi = bufs[flip ^ 1]; flip ^= 1;
      k_phase<<<dim3(16, 32), TPB, 0, stream>>>(2, W1bf, pi, po, cp2, t,
          u1, fcur, fprev, ycur, ksum, rk, 0, s, csv[s], 0.f, 1.f);
    }
    // P4: df partials = (sig'(u1)*du1) @ W2_state, t-coef 1; RK bookkeeping
    {
      float* po = bufs[flip]; const float* pi = bufs[flip ^ 1]; flip ^= 1;
      k_phase<<<dim3(16, 32), TPB, 0, stream>>>(3, W2bf, pi, po, cp2, t,
          u1, fcur, fprev, ycur, ksum, rk, 0, s, csv[s], 0.f, 1.f);
    }
  }
  k_last<<<32, 128, 0, stream>>>(bufs[flip ^ 1], ycur, rk, out);
  k_out<<<1, 64, 0, stream>>>(rk, t, out);
}